// Round 2
// baseline (704.342 us; speedup 1.0000x reference)
//
#include <hip/hip_runtime.h>
#include <hip/hip_bf16.h>

#define TT 8192
#define DD 2048
#define HH 1408
#define EE 8
#define KTOP 2
#define NA (TT * KTOP)  // 16384 assignments

typedef __attribute__((ext_vector_type(8))) short bh8;   // 8 bf16 = 4 VGPR
typedef __attribute__((ext_vector_type(4))) float f4;    // MFMA accumulator

typedef __attribute__((address_space(1))) const void gconst_t;
typedef __attribute__((address_space(3))) void lds_t;

__device__ __forceinline__ void glds16(const void* g, void* l) {
  __builtin_amdgcn_global_load_lds((gconst_t*)g, (lds_t*)l, 16, 0, 0);
}

__device__ __forceinline__ float silu_f(float x) { return x / (1.f + __expf(-x)); }

// ---------------- bookkeeping kernels ----------------
__global__ void k_init(int* counts) {
  int i = threadIdx.x;
  if (i < EE) counts[i] = 0;
}

__global__ void k_count(const int* __restrict__ idx, int* __restrict__ counts) {
  int i = blockIdx.x * 256 + threadIdx.x;
  if (i < NA) atomicAdd(&counts[idx[i]], 1);
}

__global__ void k_scan(const int* __restrict__ counts, int* __restrict__ off,
                       int* __restrict__ cursor) {
  if (threadIdx.x == 0) {
    int a = 0;
    for (int e = 0; e < EE; ++e) { off[e] = a; cursor[e] = a; a += counts[e]; }
    off[EE] = a;
  }
}

__global__ void k_scatter(const int* __restrict__ idx, const float* __restrict__ sc,
                          int* __restrict__ cursor, int* __restrict__ rows_token,
                          float* __restrict__ rows_score) {
  int i = blockIdx.x * 256 + threadIdx.x;
  if (i < NA) {
    int e = idx[i];
    int p = atomicAdd(&cursor[e], 1);
    rows_token[p] = i / KTOP;
    rows_score[p] = sc[i];
  }
}

// ---------------- conversion kernels ----------------
__global__ void k_cvtx(const float* __restrict__ src, __hip_bfloat16* __restrict__ dst) {
  int i = blockIdx.x * 256 + threadIdx.x;  // indexes float4
  const int n4 = TT * DD / 4;
  if (i < n4) {
    float4 v = reinterpret_cast<const float4*>(src)[i];
    union { ushort4 u; __hip_bfloat16 h[4]; } o;
    o.h[0] = __float2bfloat16(v.x); o.h[1] = __float2bfloat16(v.y);
    o.h[2] = __float2bfloat16(v.z); o.h[3] = __float2bfloat16(v.w);
    reinterpret_cast<ushort4*>(dst)[i] = o.u;
  }
}

// transpose+convert: src fp32 [B][R][C] -> dst bf16 [B][C][R]
__global__ void k_tc(const float* __restrict__ src, __hip_bfloat16* __restrict__ dst,
                     int R, int C) {
  __shared__ float t[32][33];
  const float* s = src + (size_t)blockIdx.z * R * C;
  __hip_bfloat16* d = dst + (size_t)blockIdx.z * R * C;
  int c0 = blockIdx.x * 32, r0 = blockIdx.y * 32;
  int x = threadIdx.x;
  for (int j = threadIdx.y; j < 32; j += 8)
    t[j][x] = s[(size_t)(r0 + j) * C + c0 + x];
  __syncthreads();
  for (int j = threadIdx.y; j < 32; j += 8)
    d[(size_t)(c0 + j) * R + r0 + x] = __float2bfloat16(t[x][j]);
}

// ---------------- 256x256 8-phase grouped GEMM ----------------
// MODE 1: h = silu(Xe*Wg) * (Xe*Wu).  A = gathered xb rows [ne][DD];
//   B-tile cols c in [0,256): tensor=(c>>5)&1 (0=gate,1=up), h=n0+((c>>6)<<5)+(c&31)
// MODE 2: y[token] += score * (h_e * Wd_e).  A = hbuf [ne][HH]; B = Wdb [E][DD][HH]
// 512 thr = 8 waves (2m x 4n); wave tile 128x64; BK=64; LDS 128 KiB dbuf.
#define QUAD(mh, nh)                                                              \
  do {                                                                            \
    _Pragma("unroll") for (int ks = 0; ks < 2; ++ks)                              \
    _Pragma("unroll") for (int i = 0; i < 4; ++i)                                 \
    _Pragma("unroll") for (int jn = 0; jn < 2; ++jn)                              \
      acc[(mh)*4 + i][(nh)*2 + jn] = __builtin_amdgcn_mfma_f32_16x16x32_bf16(     \
          af[i][ks], bf[(nh)*2 + jn][ks], acc[(mh)*4 + i][(nh)*2 + jn], 0, 0, 0); \
  } while (0)

#define BAR __builtin_amdgcn_s_barrier()
#define WLG                                             \
  do {                                                  \
    asm volatile("s_waitcnt lgkmcnt(0)" ::: "memory");  \
    __builtin_amdgcn_sched_barrier(0);                  \
  } while (0)

template <int MODE>
__global__ __launch_bounds__(512, 2) void k_gemm8(
    const __hip_bfloat16* __restrict__ Ag,
    const __hip_bfloat16* __restrict__ Bg,
    const __hip_bfloat16* __restrict__ Bu,
    const int* __restrict__ rows_token,
    const float* __restrict__ rows_score,
    const int* __restrict__ off,
    __hip_bfloat16* __restrict__ hout,
    float* __restrict__ y) {
  constexpr int KD = (MODE == 1) ? DD : HH;
  constexpr int NT = KD / 64;
  const int e = blockIdx.z;
  const int oe = off[e];
  const int ne = off[e + 1] - oe;
  const int m0 = blockIdx.y << 8;
  if (m0 >= ne) return;
  const int n0 = blockIdx.x * ((MODE == 1) ? 128 : 256);
  const int tid = threadIdx.x;
  const int lane = tid & 63;
  const int w = tid >> 6;
  const int wm = w >> 2, wn = w & 3;
  const int l3 = lane >> 3;
  const int chunk = (lane & 7) ^ l3;  // pre-swizzled source chunk (rule #21)
  const int l15 = lane & 15;
  const int l4 = lane >> 4;

  __shared__ __hip_bfloat16 lds[65536];  // A: [2buf][2half][128r][64], B at +32768

  // per-thread stage source pointers [half][j]
  const __hip_bfloat16* asrc[2][2];
  const __hip_bfloat16* bsrc[2][2];
#pragma unroll
  for (int h = 0; h < 2; ++h)
#pragma unroll
    for (int j = 0; j < 2; ++j) {
      int r = h * 128 + ((2 * w + j) << 3) + l3;
      int rr = m0 + r; if (rr >= ne) rr = ne - 1;
      if constexpr (MODE == 1)
        asrc[h][j] = Ag + (size_t)rows_token[oe + rr] * DD + chunk * 8;
      else
        asrc[h][j] = Ag + (size_t)(oe + rr) * HH + chunk * 8;
      if constexpr (MODE == 1) {
        int ts = (r >> 5) & 1;
        int hc = n0 + ((r >> 6) << 5) + (r & 31);
        bsrc[h][j] = (ts ? Bu : Bg) + ((size_t)e * HH + hc) * DD + chunk * 8;
      } else {
        bsrc[h][j] = Bg + ((size_t)e * DD + (n0 + r)) * HH + chunk * 8;
      }
    }

  __hip_bfloat16* const aldsb = lds + (w << 10);          // wave's 2-group slot
  __hip_bfloat16* const bldsb = lds + 32768 + (w << 10);

  auto stageA = [&](int u, int h) {
    const int k0 = u << 6;
    __hip_bfloat16* d = aldsb + ((u & 1) << 14) + (h << 13);
    glds16(asrc[h][0] + k0, d);
    glds16(asrc[h][1] + k0, d + 512);
  };
  auto stageB = [&](int u, int h) {
    const int k0 = u << 6;
    __hip_bfloat16* d = bldsb + ((u & 1) << 14) + (h << 13);
    glds16(bsrc[h][0] + k0, d);
    glds16(bsrc[h][1] + k0, d + 512);
  };

  f4 acc[8][4];
#pragma unroll
  for (int mf = 0; mf < 8; ++mf)
#pragma unroll
    for (int nf = 0; nf < 4; ++nf) acc[mf][nf] = (f4){0.f, 0.f, 0.f, 0.f};
  bh8 af[4][2], bf[4][2];

  auto ldA = [&](int buf, int mh) {
#pragma unroll
    for (int i = 0; i < 4; ++i) {
      int row = wm * 128 + mh * 64 + i * 16 + l15;
      const char* base = (const char*)lds + buf * 32768 + (row >> 7) * 16384 +
                         (row & 127) * 128;
      int sw = (row & 7) << 4;
#pragma unroll
      for (int ks = 0; ks < 2; ++ks)
        af[i][ks] = *(const bh8*)(base + ((((ks * 4 + l4) << 4)) ^ sw));
    }
  };
  auto ldB = [&](int buf, int nh) {
#pragma unroll
    for (int i = 0; i < 2; ++i) {
      int row = wn * 64 + nh * 32 + i * 16 + l15;
      const char* base = (const char*)lds + 65536 + buf * 32768 +
                         (row >> 7) * 16384 + (row & 127) * 128;
      int sw = (row & 7) << 4;
#pragma unroll
      for (int ks = 0; ks < 2; ++ks)
        bf[nh * 2 + i][ks] = *(const bh8*)(base + ((((ks * 4 + l4) << 4)) ^ sw));
    }
  };

  // prologue: stage B0(0),B1(0),A0(0),A1(0),B0(1),B1(1) = 12 loads/thread-pairs
  stageB(0, 0); stageB(0, 1); stageA(0, 0); stageA(0, 1); stageB(1, 0); stageB(1, 1);
  asm volatile("s_waitcnt vmcnt(4)" ::: "memory");
  BAR;

  for (int t = 0; t < NT; ++t) {
    const int buf = t & 1;
    // P0: read A-mh0 + B-nh0 of tile t; stage A0(t+1)
    ldA(buf, 0); ldB(buf, 0);
    if (t + 1 < NT) stageA(t + 1, 0);
    BAR; WLG;
    __builtin_amdgcn_s_setprio(1); QUAD(0, 0); __builtin_amdgcn_s_setprio(0);
    BAR;
    // P1: read B-nh1; stage A1(t+1)
    ldB(buf, 1);
    if (t + 1 < NT) stageA(t + 1, 1);
    BAR; WLG;
    __builtin_amdgcn_s_setprio(1); QUAD(0, 1); __builtin_amdgcn_s_setprio(0);
    BAR;
    // P2: read A-mh1; stage B0(t+2)
    ldA(buf, 1);
    if (t + 2 < NT) stageB(t + 2, 0);
    BAR; WLG;
    __builtin_amdgcn_s_setprio(1); QUAD(1, 1); __builtin_amdgcn_s_setprio(0);
    BAR;
    // P3: stage B1(t+2); counted vmcnt covers tile t+1's reads
    if (t + 2 < NT) stageB(t + 2, 1);
    if (t == NT - 2) asm volatile("s_waitcnt vmcnt(0)" ::: "memory");
    else if (t < NT - 2) asm volatile("s_waitcnt vmcnt(4)" ::: "memory");
    BAR;
    __builtin_amdgcn_s_setprio(1); QUAD(1, 0); __builtin_amdgcn_s_setprio(0);
    BAR;
  }

  // epilogue
  if constexpr (MODE == 1) {
    const int hb0 = n0 + wn * 32 + l15;
#pragma unroll
    for (int mf = 0; mf < 8; ++mf) {
#pragma unroll
      for (int reg = 0; reg < 4; ++reg) {
        int r = m0 + wm * 128 + mf * 16 + (l4 << 2) + reg;
        if (r < ne) {
          size_t hrow = (size_t)(oe + r) * HH;
#pragma unroll
          for (int jn = 0; jn < 2; ++jn) {
            float g = acc[mf][jn][reg];
            float u = acc[mf][jn + 2][reg];
            hout[hrow + hb0 + jn * 16] = __float2bfloat16(silu_f(g) * u);
          }
        }
      }
    }
  } else {
#pragma unroll
    for (int mf = 0; mf < 8; ++mf) {
#pragma unroll
      for (int reg = 0; reg < 4; ++reg) {
        int r = m0 + wm * 128 + mf * 16 + (l4 << 2) + reg;
        if (r < ne) {
          int tok = rows_token[oe + r];
          float sc = rows_score[oe + r];
          float* yr = y + (size_t)tok * DD + n0 + wn * 64 + l15;
#pragma unroll
          for (int nf = 0; nf < 4; ++nf)
            atomicAdd(yr + nf * 16, sc * acc[mf][nf][reg]);
        }
      }
    }
  }
}

// ---------------- launch ----------------
extern "C" void kernel_launch(void* const* d_in, const int* in_sizes, int n_in,
                              void* d_out, int out_size, void* d_ws, size_t ws_size,
                              hipStream_t stream) {
  const float* x = (const float*)d_in[0];
  const int* topk_idx = (const int*)d_in[1];
  const float* topk_sc = (const float*)d_in[2];
  const float* Wg = (const float*)d_in[3];
  const float* Wu = (const float*)d_in[4];
  const float* Wd = (const float*)d_in[5];
  float* y = (float*)d_out;

  char* p = (char*)d_ws;
  auto take = [&](size_t b) { char* r = p; p += (b + 255) & ~(size_t)255; return r; };
  int* counts = (int*)take(EE * 4);
  int* cursor = (int*)take(EE * 4);
  int* off = (int*)take((EE + 1) * 4);
  int* rows_token = (int*)take((size_t)NA * 4);
  float* rows_score = (float*)take((size_t)NA * 4);
  __hip_bfloat16* xb = (__hip_bfloat16*)take((size_t)TT * DD * 2);
  __hip_bfloat16* Wgb = (__hip_bfloat16*)take((size_t)EE * DD * HH * 2);
  __hip_bfloat16* Wub = (__hip_bfloat16*)take((size_t)EE * DD * HH * 2);
  __hip_bfloat16* Wdb = (__hip_bfloat16*)take((size_t)EE * DD * HH * 2);
  __hip_bfloat16* hbuf = (__hip_bfloat16*)take((size_t)NA * HH * 2);

  hipMemsetAsync(d_out, 0, (size_t)TT * DD * 4, stream);
  k_init<<<1, 64, 0, stream>>>(counts);
  k_count<<<NA / 256, 256, 0, stream>>>(topk_idx, counts);
  k_scan<<<1, 1, 0, stream>>>(counts, off, cursor);
  k_scatter<<<NA / 256, 256, 0, stream>>>(topk_idx, topk_sc, cursor, rows_token, rows_score);
  k_cvtx<<<TT * DD / 4 / 256, 256, 0, stream>>>(x, xb);
  dim3 tg(HH / 32, DD / 32, EE);
  k_tc<<<tg, dim3(32, 8), 0, stream>>>(Wg, Wgb, DD, HH);
  k_tc<<<tg, dim3(32, 8), 0, stream>>>(Wu, Wub, DD, HH);
  dim3 td(DD / 32, HH / 32, EE);
  k_tc<<<td, dim3(32, 8), 0, stream>>>(Wd, Wdb, HH, DD);
  k_gemm8<1><<<dim3(HH / 128, 10, EE), 512, 0, stream>>>(
      xb, Wgb, Wub, rows_token, rows_score, off, hbuf, nullptr);
  k_gemm8<2><<<dim3(DD / 256, 10, EE), 512, 0, stream>>>(
      hbuf, Wdb, nullptr, rows_token, rows_score, off, nullptr, y);
}

// Round 3
// 682.555 us; speedup vs baseline: 1.0319x; 1.0319x over previous
//
#include <hip/hip_runtime.h>
#include <hip/hip_bf16.h>

#define TT 8192
#define DD 2048
#define HH 1408
#define EE 8
#define KTOP 2
#define NA (TT * KTOP)  // 16384 assignments

typedef __attribute__((ext_vector_type(8))) short bh8;   // 8 bf16 = 4 VGPR
typedef __attribute__((ext_vector_type(4))) float f4;    // MFMA accumulator

typedef __attribute__((address_space(1))) const void gconst_t;
typedef __attribute__((address_space(3))) void lds_t;

__device__ __forceinline__ void glds16(const void* g, void* l) {
  __builtin_amdgcn_global_load_lds((gconst_t*)g, (lds_t*)l, 16, 0, 0);
}

__device__ __forceinline__ float silu_f(float x) { return x / (1.f + __expf(-x)); }

// ---------------- bookkeeping kernels ----------------
__global__ void k_init(int* counts) {
  int i = threadIdx.x;
  if (i < EE) counts[i] = 0;
}

__global__ void k_count(const int* __restrict__ idx, int* __restrict__ counts) {
  int i = blockIdx.x * 256 + threadIdx.x;
  if (i < NA) atomicAdd(&counts[idx[i]], 1);
}

__global__ void k_scan(const int* __restrict__ counts, int* __restrict__ off,
                       int* __restrict__ cursor) {
  if (threadIdx.x == 0) {
    int a = 0;
    for (int e = 0; e < EE; ++e) { off[e] = a; cursor[e] = a; a += counts[e]; }
    off[EE] = a;
  }
}

__global__ void k_scatter(const int* __restrict__ idx, const float* __restrict__ sc,
                          int* __restrict__ cursor, int* __restrict__ rows_token,
                          float* __restrict__ rows_score, int* __restrict__ pos) {
  int i = blockIdx.x * 256 + threadIdx.x;
  if (i < NA) {
    int e = idx[i];
    int p = atomicAdd(&cursor[e], 1);
    rows_token[p] = i / KTOP;
    rows_score[p] = sc[i];
    pos[i] = p;
  }
}

// ---------------- conversion kernels ----------------
__global__ void k_cvtx(const float* __restrict__ src, __hip_bfloat16* __restrict__ dst) {
  int i = blockIdx.x * 256 + threadIdx.x;  // indexes float4
  const int n4 = TT * DD / 4;
  if (i < n4) {
    float4 v = reinterpret_cast<const float4*>(src)[i];
    union { ushort4 u; __hip_bfloat16 h[4]; } o;
    o.h[0] = __float2bfloat16(v.x); o.h[1] = __float2bfloat16(v.y);
    o.h[2] = __float2bfloat16(v.z); o.h[3] = __float2bfloat16(v.w);
    reinterpret_cast<ushort4*>(dst)[i] = o.u;
  }
}

// transpose+convert: src fp32 [B][R][C] -> dst bf16 [B][C][R]
__global__ void k_tc(const float* __restrict__ src, __hip_bfloat16* __restrict__ dst,
                     int R, int C) {
  __shared__ float t[32][33];
  const float* s = src + (size_t)blockIdx.z * R * C;
  __hip_bfloat16* d = dst + (size_t)blockIdx.z * R * C;
  int c0 = blockIdx.x * 32, r0 = blockIdx.y * 32;
  int x = threadIdx.x;
  for (int j = threadIdx.y; j < 32; j += 8)
    t[j][x] = s[(size_t)(r0 + j) * C + c0 + x];
  __syncthreads();
  for (int j = threadIdx.y; j < 32; j += 8)
    d[(size_t)(c0 + j) * R + r0 + x] = __float2bfloat16(t[x][j]);
}

// combine: y[t] = fp32(ybuf[pos[2t]]) + fp32(ybuf[pos[2t+1]])  (scores pre-folded)
__global__ void k_combine(const __hip_bfloat16* __restrict__ ybuf,
                          const int* __restrict__ pos, float* __restrict__ y) {
  int i = blockIdx.x * 256 + threadIdx.x;  // over TT * DD/8
  int t = i >> 8;                          // DD/8 == 256
  int d0 = (i & 255) << 3;
  const uint4 a = *reinterpret_cast<const uint4*>(ybuf + (size_t)pos[2 * t] * DD + d0);
  const uint4 b = *reinterpret_cast<const uint4*>(ybuf + (size_t)pos[2 * t + 1] * DD + d0);
  float* o = y + (size_t)t * DD + d0;
  unsigned au[4] = {a.x, a.y, a.z, a.w}, bu[4] = {b.x, b.y, b.z, b.w};
  float r[8];
#pragma unroll
  for (int j = 0; j < 4; ++j) {
    r[2 * j] = __uint_as_float(au[j] << 16) + __uint_as_float(bu[j] << 16);
    r[2 * j + 1] = __uint_as_float(au[j] & 0xffff0000u) + __uint_as_float(bu[j] & 0xffff0000u);
  }
  reinterpret_cast<float4*>(o)[0] = (float4){r[0], r[1], r[2], r[3]};
  reinterpret_cast<float4*>(o)[1] = (float4){r[4], r[5], r[6], r[7]};
}

// ---------------- 256x256 8-phase grouped GEMM ----------------
// MODE 1: h = silu(Xe*Wg) * (Xe*Wu).  A = gathered xb rows [ne][DD];
//   B-tile cols c in [0,256): tensor=(c>>5)&1 (0=gate,1=up), h=n0+((c>>6)<<5)+(c&31)
// MODE 2: ybuf[row] = score * (h_e * Wd_e) in bf16.  A = hbuf [ne][HH]; B = Wdb [E][DD][HH]
// 512 thr = 8 waves (2m x 4n); wave tile 128x64; BK=64; LDS 128 KiB dbuf.
// Staging discipline: all of tile t+2 staged at P2 (B) / P3 (A) into the buffer
// whose reads just completed; vmcnt(8) at P3 covers tile t+1 (issued 4-6 phases ago).
#define QUAD(mh, nh)                                                              \
  do {                                                                            \
    _Pragma("unroll") for (int ks = 0; ks < 2; ++ks)                              \
    _Pragma("unroll") for (int i = 0; i < 4; ++i)                                 \
    _Pragma("unroll") for (int jn = 0; jn < 2; ++jn)                              \
      acc[(mh)*4 + i][(nh)*2 + jn] = __builtin_amdgcn_mfma_f32_16x16x32_bf16(     \
          af[i][ks], bf[(nh)*2 + jn][ks], acc[(mh)*4 + i][(nh)*2 + jn], 0, 0, 0); \
  } while (0)

#define BAR __builtin_amdgcn_s_barrier()
#define WLG                                             \
  do {                                                  \
    asm volatile("s_waitcnt lgkmcnt(0)" ::: "memory");  \
    __builtin_amdgcn_sched_barrier(0);                  \
  } while (0)

template <int MODE>
__global__ __launch_bounds__(512, 2) void k_gemm8(
    const __hip_bfloat16* __restrict__ Ag,
    const __hip_bfloat16* __restrict__ Bg,
    const __hip_bfloat16* __restrict__ Bu,
    const int* __restrict__ rows_token,
    const float* __restrict__ rows_score,
    const int* __restrict__ off,
    __hip_bfloat16* __restrict__ hout,
    __hip_bfloat16* __restrict__ ybuf) {
  constexpr int KD = (MODE == 1) ? DD : HH;
  constexpr int NT = KD / 64;
  const int e = blockIdx.z;
  const int oe = off[e];
  const int ne = off[e + 1] - oe;
  const int n0 = blockIdx.x * ((MODE == 1) ? 128 : 256);
  const int tid = threadIdx.x;
  const int lane = tid & 63;
  const int w = tid >> 6;
  const int wm = w >> 2, wn = w & 3;
  const int l3 = lane >> 3;
  const int chunk = (lane & 7) ^ l3;  // pre-swizzled source chunk (rule #21)
  const int l15 = lane & 15;
  const int l4 = lane >> 4;

  __shared__ __hip_bfloat16 lds[65536];  // A: [2buf][2half][128r][64], B at +32768

  __hip_bfloat16* const aldsb = lds + (w << 10);          // wave's 2-group slot
  __hip_bfloat16* const bldsb = lds + 32768 + (w << 10);

  for (int m0 = blockIdx.y << 8; m0 < ne; m0 += gridDim.y << 8) {
    // per-thread stage source pointers [half][j]
    const __hip_bfloat16* asrc[2][2];
    const __hip_bfloat16* bsrc[2][2];
#pragma unroll
    for (int h = 0; h < 2; ++h)
#pragma unroll
      for (int j = 0; j < 2; ++j) {
        int r = h * 128 + ((2 * w + j) << 3) + l3;
        int rr = m0 + r; if (rr >= ne) rr = ne - 1;
        if constexpr (MODE == 1)
          asrc[h][j] = Ag + (size_t)rows_token[oe + rr] * DD + chunk * 8;
        else
          asrc[h][j] = Ag + (size_t)(oe + rr) * HH + chunk * 8;
        if constexpr (MODE == 1) {
          int ts = (r >> 5) & 1;
          int hc = n0 + ((r >> 6) << 5) + (r & 31);
          bsrc[h][j] = (ts ? Bu : Bg) + ((size_t)e * HH + hc) * DD + chunk * 8;
        } else {
          bsrc[h][j] = Bg + ((size_t)e * DD + (n0 + r)) * HH + chunk * 8;
        }
      }

    auto stageA = [&](int u, int h) {
      const int k0 = u << 6;
      __hip_bfloat16* d = aldsb + ((u & 1) << 14) + (h << 13);
      glds16(asrc[h][0] + k0, d);
      glds16(asrc[h][1] + k0, d + 512);
    };
    auto stageB = [&](int u, int h) {
      const int k0 = u << 6;
      __hip_bfloat16* d = bldsb + ((u & 1) << 14) + (h << 13);
      glds16(bsrc[h][0] + k0, d);
      glds16(bsrc[h][1] + k0, d + 512);
    };

    f4 acc[8][4];
#pragma unroll
    for (int mf = 0; mf < 8; ++mf)
#pragma unroll
      for (int nf = 0; nf < 4; ++nf) acc[mf][nf] = (f4){0.f, 0.f, 0.f, 0.f};
    bh8 af[4][2], bf[4][2];

    auto ldA = [&](int buf, int mh) {
#pragma unroll
      for (int i = 0; i < 4; ++i) {
        int row = wm * 128 + mh * 64 + i * 16 + l15;
        const char* base = (const char*)lds + buf * 32768 + (row >> 7) * 16384 +
                           (row & 127) * 128;
        int sw = (row & 7) << 4;
#pragma unroll
        for (int ks = 0; ks < 2; ++ks)
          af[i][ks] = *(const bh8*)(base + ((((ks * 4 + l4) << 4)) ^ sw));
      }
    };
    auto ldB = [&](int buf, int nh) {
#pragma unroll
      for (int i = 0; i < 2; ++i) {
        int row = wn * 64 + nh * 32 + i * 16 + l15;
        const char* base = (const char*)lds + 65536 + buf * 32768 +
                           (row >> 7) * 16384 + (row & 127) * 128;
        int sw = (row & 7) << 4;
#pragma unroll
        for (int ks = 0; ks < 2; ++ks)
          bf[nh * 2 + i][ks] = *(const bh8*)(base + ((((ks * 4 + l4) << 4)) ^ sw));
      }
    };

    // prologue: tile0 (A,B) then tile1 (B,A) = 16 loads; wait tile0 (8 left)
    stageA(0, 0); stageA(0, 1); stageB(0, 0); stageB(0, 1);
    stageB(1, 0); stageB(1, 1); stageA(1, 0); stageA(1, 1);
    asm volatile("s_waitcnt vmcnt(8)" ::: "memory");
    BAR;

    for (int t = 0; t < NT; ++t) {
      const int buf = t & 1;
      // P0: read A-mh0 + B-nh0 of tile t
      ldA(buf, 0); ldB(buf, 0);
      BAR; WLG;
      __builtin_amdgcn_s_setprio(1); QUAD(0, 0); __builtin_amdgcn_s_setprio(0);
      BAR;
      // P1: read B-nh1
      ldB(buf, 1);
      BAR; WLG;
      __builtin_amdgcn_s_setprio(1); QUAD(0, 1); __builtin_amdgcn_s_setprio(0);
      BAR;
      // P2: read A-mh1; stage B(t+2) (B region of buf free after P1)
      ldA(buf, 1);
      if (t + 2 < NT) { stageB(t + 2, 0); stageB(t + 2, 1); }
      BAR; WLG;
      __builtin_amdgcn_s_setprio(1); QUAD(1, 1); __builtin_amdgcn_s_setprio(0);
      BAR;
      // P3: stage A(t+2) (A region of buf free after P2); wait tile t+1
      if (t + 2 < NT) { stageA(t + 2, 0); stageA(t + 2, 1); }
      if (t < NT - 2) asm volatile("s_waitcnt vmcnt(8)" ::: "memory");
      else if (t == NT - 2) asm volatile("s_waitcnt vmcnt(0)" ::: "memory");
      BAR;
      __builtin_amdgcn_s_setprio(1); QUAD(1, 0); __builtin_amdgcn_s_setprio(0);
      BAR;
    }

    // epilogue
    if constexpr (MODE == 1) {
      const int hb0 = n0 + wn * 32 + l15;
#pragma unroll
      for (int mf = 0; mf < 8; ++mf) {
#pragma unroll
        for (int reg = 0; reg < 4; ++reg) {
          int r = m0 + wm * 128 + mf * 16 + (l4 << 2) + reg;
          if (r < ne) {
            size_t hrow = (size_t)(oe + r) * HH;
#pragma unroll
            for (int jn = 0; jn < 2; ++jn) {
              float g = acc[mf][jn][reg];
              float u = acc[mf][jn + 2][reg];
              hout[hrow + hb0 + jn * 16] = __float2bfloat16(silu_f(g) * u);
            }
          }
        }
      }
    } else {
#pragma unroll
      for (int mf = 0; mf < 8; ++mf) {
#pragma unroll
        for (int reg = 0; reg < 4; ++reg) {
          int r = m0 + wm * 128 + mf * 16 + (l4 << 2) + reg;
          if (r < ne) {
            float sc = rows_score[oe + r];
            __hip_bfloat16* yr = ybuf + (size_t)(oe + r) * DD + n0 + wn * 64 + l15;
#pragma unroll
            for (int nf = 0; nf < 4; ++nf)
              yr[nf * 16] = __float2bfloat16(sc * acc[mf][nf][reg]);
          }
        }
      }
    }
  }
}

// ---------------- launch ----------------
extern "C" void kernel_launch(void* const* d_in, const int* in_sizes, int n_in,
                              void* d_out, int out_size, void* d_ws, size_t ws_size,
                              hipStream_t stream) {
  const float* x = (const float*)d_in[0];
  const int* topk_idx = (const int*)d_in[1];
  const float* topk_sc = (const float*)d_in[2];
  const float* Wg = (const float*)d_in[3];
  const float* Wu = (const float*)d_in[4];
  const float* Wd = (const float*)d_in[5];
  float* y = (float*)d_out;

  char* p = (char*)d_ws;
  auto take = [&](size_t b) { char* r = p; p += (b + 255) & ~(size_t)255; return r; };
  int* counts = (int*)take(EE * 4);
  int* cursor = (int*)take(EE * 4);
  int* off = (int*)take((EE + 1) * 4);
  int* rows_token = (int*)take((size_t)NA * 4);
  float* rows_score = (float*)take((size_t)NA * 4);
  int* pos = (int*)take((size_t)NA * 4);
  __hip_bfloat16* xb = (__hip_bfloat16*)take((size_t)TT * DD * 2);
  __hip_bfloat16* Wgb = (__hip_bfloat16*)take((size_t)EE * DD * HH * 2);
  __hip_bfloat16* Wub = (__hip_bfloat16*)take((size_t)EE * DD * HH * 2);
  __hip_bfloat16* Wdb = (__hip_bfloat16*)take((size_t)EE * DD * HH * 2);
  __hip_bfloat16* hbuf = (__hip_bfloat16*)take((size_t)NA * HH * 2);
  __hip_bfloat16* ybuf = (__hip_bfloat16*)take((size_t)NA * DD * 2);

  k_init<<<1, 64, 0, stream>>>(counts);
  k_count<<<NA / 256, 256, 0, stream>>>(topk_idx, counts);
  k_scan<<<1, 1, 0, stream>>>(counts, off, cursor);
  k_scatter<<<NA / 256, 256, 0, stream>>>(topk_idx, topk_sc, cursor, rows_token,
                                          rows_score, pos);
  k_cvtx<<<TT * DD / 4 / 256, 256, 0, stream>>>(x, xb);
  dim3 tg(HH / 32, DD / 32, EE);
  k_tc<<<tg, dim3(32, 8), 0, stream>>>(Wg, Wgb, DD, HH);
  k_tc<<<tg, dim3(32, 8), 0, stream>>>(Wu, Wub, DD, HH);
  dim3 td(DD / 32, HH / 32, EE);
  k_tc<<<td, dim3(32, 8), 0, stream>>>(Wd, Wdb, HH, DD);
  k_gemm8<1><<<dim3(HH / 128, 10, EE), 512, 0, stream>>>(
      xb, Wgb, Wub, rows_token, rows_score, off, hbuf, nullptr);
  k_gemm8<2><<<dim3(DD / 256, 10, EE), 512, 0, stream>>>(
      hbuf, Wdb, nullptr, rows_token, rows_score, off, nullptr, ybuf);
  k_combine<<<TT * (DD / 8) / 256, 256, 0, stream>>>(ybuf, pos, y);
}

// Round 4
// 675.856 us; speedup vs baseline: 1.0421x; 1.0099x over previous
//
#include <hip/hip_runtime.h>
#include <hip/hip_bf16.h>

#define TT 8192
#define DD 2048
#define HH 1408
#define EE 8
#define KTOP 2
#define NA (TT * KTOP)  // 16384 assignments

typedef __attribute__((ext_vector_type(8))) short bh8;   // 8 bf16 = 4 VGPR
typedef __attribute__((ext_vector_type(4))) float f4;    // MFMA accumulator

typedef __attribute__((address_space(1))) const void gconst_t;
typedef __attribute__((address_space(3))) void lds_t;

__device__ __forceinline__ void glds16(const void* g, void* l) {
  __builtin_amdgcn_global_load_lds((gconst_t*)g, (lds_t*)l, 16, 0, 0);
}

__device__ __forceinline__ float silu_f(float x) { return x / (1.f + __expf(-x)); }

// ---------------- bookkeeping kernels ----------------
__global__ void k_init(int* counts) {
  int i = threadIdx.x;
  if (i < EE) counts[i] = 0;
}

__global__ void k_count(const int* __restrict__ idx, int* __restrict__ counts) {
  int i = blockIdx.x * 256 + threadIdx.x;
  if (i < NA) atomicAdd(&counts[idx[i]], 1);
}

__global__ void k_scan(const int* __restrict__ counts, int* __restrict__ off,
                       int* __restrict__ cursor) {
  if (threadIdx.x == 0) {
    int a = 0;
    for (int e = 0; e < EE; ++e) { off[e] = a; cursor[e] = a; a += counts[e]; }
    off[EE] = a;
  }
}

__global__ void k_scatter(const int* __restrict__ idx, const float* __restrict__ sc,
                          int* __restrict__ cursor, int* __restrict__ rows_token,
                          float* __restrict__ rows_score, int* __restrict__ pos) {
  int i = blockIdx.x * 256 + threadIdx.x;
  if (i < NA) {
    int e = idx[i];
    int p = atomicAdd(&cursor[e], 1);
    rows_token[p] = i / KTOP;
    rows_score[p] = sc[i];
    pos[i] = p;
  }
}

// ---------------- conversion kernels ----------------
__global__ void k_cvtx(const float* __restrict__ src, __hip_bfloat16* __restrict__ dst) {
  int i = blockIdx.x * 256 + threadIdx.x;  // indexes float4
  const int n4 = TT * DD / 4;
  if (i < n4) {
    float4 v = reinterpret_cast<const float4*>(src)[i];
    union { ushort4 u; __hip_bfloat16 h[4]; } o;
    o.h[0] = __float2bfloat16(v.x); o.h[1] = __float2bfloat16(v.y);
    o.h[2] = __float2bfloat16(v.z); o.h[3] = __float2bfloat16(v.w);
    reinterpret_cast<ushort4*>(dst)[i] = o.u;
  }
}

// transpose+convert: src fp32 [B][R][C] -> dst bf16 [B][C][R]
__global__ void k_tc(const float* __restrict__ src, __hip_bfloat16* __restrict__ dst,
                     int R, int C) {
  __shared__ float t[32][33];
  const float* s = src + (size_t)blockIdx.z * R * C;
  __hip_bfloat16* d = dst + (size_t)blockIdx.z * R * C;
  int c0 = blockIdx.x * 32, r0 = blockIdx.y * 32;
  int x = threadIdx.x;
  for (int j = threadIdx.y; j < 32; j += 8)
    t[j][x] = s[(size_t)(r0 + j) * C + c0 + x];
  __syncthreads();
  for (int j = threadIdx.y; j < 32; j += 8)
    d[(size_t)(c0 + j) * R + r0 + x] = __float2bfloat16(t[x][j]);
}

// combine: y[t] = fp32(ybuf[pos[2t]]) + fp32(ybuf[pos[2t+1]])  (scores pre-folded)
__global__ void k_combine(const __hip_bfloat16* __restrict__ ybuf,
                          const int* __restrict__ pos, float* __restrict__ y) {
  int i = blockIdx.x * 256 + threadIdx.x;  // over TT * DD/8
  int t = i >> 8;                          // DD/8 == 256
  int d0 = (i & 255) << 3;
  const uint4 a = *reinterpret_cast<const uint4*>(ybuf + (size_t)pos[2 * t] * DD + d0);
  const uint4 b = *reinterpret_cast<const uint4*>(ybuf + (size_t)pos[2 * t + 1] * DD + d0);
  float* o = y + (size_t)t * DD + d0;
  unsigned au[4] = {a.x, a.y, a.z, a.w}, bu[4] = {b.x, b.y, b.z, b.w};
  float r[8];
#pragma unroll
  for (int j = 0; j < 4; ++j) {
    r[2 * j] = __uint_as_float(au[j] << 16) + __uint_as_float(bu[j] << 16);
    r[2 * j + 1] = __uint_as_float(au[j] & 0xffff0000u) + __uint_as_float(bu[j] & 0xffff0000u);
  }
  reinterpret_cast<float4*>(o)[0] = (float4){r[0], r[1], r[2], r[3]};
  reinterpret_cast<float4*>(o)[1] = (float4){r[4], r[5], r[6], r[7]};
}

// XCD-bijective swizzle (m204): HW assigns orig%8 -> XCD; give each XCD a
// contiguous wgid chunk. nwg must be divisible by 8 (true by construction).
__device__ __forceinline__ int xcd_swz(int orig, int nwg) {
  return (orig & 7) * (nwg >> 3) + (orig >> 3);
}

// ---------------- GEMM1: h = silu(Xe*Wg) * (Xe*Wu) ----------------
// 128 rows x (64 gate + 64 up cols), BK=64, 4 waves. Round-1 verified structure.
// Grid: 1D, wgid -> (e, nb, mb) with mb fastest (consecutive blocks share B panel).
#define G1_NX 22  // HH/64
#define G1_MY 20
__global__ __launch_bounds__(256, 2) void k_gemm1(
    const __hip_bfloat16* __restrict__ xb,
    const __hip_bfloat16* __restrict__ Wgb,
    const __hip_bfloat16* __restrict__ Wub,
    const int* __restrict__ rows_token,
    const int* __restrict__ off,
    __hip_bfloat16* __restrict__ hbuf) {
  const int wg = xcd_swz(blockIdx.x, G1_NX * G1_MY * EE);
  const int e = wg / (G1_NX * G1_MY);
  const int rem = wg - e * (G1_NX * G1_MY);
  const int nb = rem / G1_MY;
  const int mb = rem - nb * G1_MY;
  const int oe = off[e];
  const int ne = off[e + 1] - oe;
  if (ne <= 0) return;
  const int n0 = nb * 64;
  const int tid = threadIdx.x;
  const int lane = tid & 63;
  const int w = tid >> 6;

  __shared__ __hip_bfloat16 As[128 * 64];
  __shared__ __hip_bfloat16 Bs[128 * 64];

  const int kel = (((lane & 7) ^ (lane >> 3)) << 3);

  const __hip_bfloat16* bsrc[4];
#pragma unroll
  for (int i = 0; i < 4; ++i) {
    int bn = ((w * 4 + i) << 3) + (lane >> 3);
    const __hip_bfloat16* base =
        (bn < 64) ? (Wgb + ((size_t)e * HH + (n0 + bn)) * DD)
                  : (Wub + ((size_t)e * HH + (n0 + bn - 64)) * DD);
    bsrc[i] = base + kel;
  }

  for (int m0 = mb * 128; m0 < ne; m0 += G1_MY * 128) {
    const __hip_bfloat16* asrc[4];
#pragma unroll
    for (int i = 0; i < 4; ++i) {
      int r = ((w * 4 + i) << 3) + (lane >> 3);
      int rr = m0 + r; rr = rr < ne ? rr : ne - 1;
      asrc[i] = xb + (size_t)rows_token[oe + rr] * DD + kel;
    }

    f4 acc[2][8];
#pragma unroll
    for (int mf = 0; mf < 2; ++mf)
#pragma unroll
      for (int nf = 0; nf < 8; ++nf)
        acc[mf][nf] = (f4){0.f, 0.f, 0.f, 0.f};

    for (int k0 = 0; k0 < DD; k0 += 64) {
#pragma unroll
      for (int i = 0; i < 4; ++i) {
        glds16(asrc[i] + k0, As + ((w * 4 + i) << 9));
        glds16(bsrc[i] + k0, Bs + ((w * 4 + i) << 9));
      }
      __syncthreads();
#pragma unroll
      for (int kk = 0; kk < 2; ++kk) {
        const int kByte = (kk * 32 + ((lane >> 4) << 3)) * 2;
        bh8 a[2], b[8];
#pragma unroll
        for (int mf = 0; mf < 2; ++mf) {
          int row = (w << 5) + mf * 16 + (lane & 15);
          int ad = row * 128 + (kByte ^ ((row & 7) << 4));
          a[mf] = *reinterpret_cast<const bh8*>(reinterpret_cast<const char*>(As) + ad);
        }
#pragma unroll
        for (int nf = 0; nf < 8; ++nf) {
          int bn = nf * 16 + (lane & 15);
          int ad = bn * 128 + (kByte ^ ((bn & 7) << 4));
          b[nf] = *reinterpret_cast<const bh8*>(reinterpret_cast<const char*>(Bs) + ad);
        }
#pragma unroll
        for (int mf = 0; mf < 2; ++mf)
#pragma unroll
          for (int nf = 0; nf < 8; ++nf)
            acc[mf][nf] = __builtin_amdgcn_mfma_f32_16x16x32_bf16(a[mf], b[nf], acc[mf][nf], 0, 0, 0);
      }
      __syncthreads();
    }

    const int cb = n0 + (lane & 15);
#pragma unroll
    for (int mf = 0; mf < 2; ++mf) {
#pragma unroll
      for (int reg = 0; reg < 4; ++reg) {
        int grow = m0 + (w << 5) + mf * 16 + ((lane >> 4) << 2) + reg;
        if (grow < ne) {
          size_t hb = (size_t)(oe + grow) * HH;
#pragma unroll
          for (int nf = 0; nf < 4; ++nf) {
            float g = acc[mf][nf][reg];
            float u = acc[mf][nf + 4][reg];
            hbuf[hb + cb + nf * 16] = __float2bfloat16(silu_f(g) * u);
          }
        }
      }
    }
  }
}

// ---------------- GEMM2: ybuf[row] = score * (h_e * Wd_e) in bf16 ----------------
#define G2_NX 16  // DD/128
#define G2_MY 20
__global__ __launch_bounds__(256, 2) void k_gemm2(
    const __hip_bfloat16* __restrict__ hbuf,
    const __hip_bfloat16* __restrict__ Wdb,
    const float* __restrict__ rows_score,
    const int* __restrict__ off,
    __hip_bfloat16* __restrict__ ybuf) {
  const int wg = xcd_swz(blockIdx.x, G2_NX * G2_MY * EE);
  const int e = wg / (G2_NX * G2_MY);
  const int rem = wg - e * (G2_NX * G2_MY);
  const int nb = rem / G2_MY;
  const int mb = rem - nb * G2_MY;
  const int oe = off[e];
  const int ne = off[e + 1] - oe;
  if (ne <= 0) return;
  const int n0 = nb * 128;
  const int tid = threadIdx.x;
  const int lane = tid & 63;
  const int w = tid >> 6;

  __shared__ __hip_bfloat16 As[128 * 64];
  __shared__ __hip_bfloat16 Bs[128 * 64];
  const int kel = (((lane & 7) ^ (lane >> 3)) << 3);

  const __hip_bfloat16* bsrc[4];
#pragma unroll
  for (int i = 0; i < 4; ++i) {
    int bn = ((w * 4 + i) << 3) + (lane >> 3);
    bsrc[i] = Wdb + ((size_t)e * DD + (n0 + bn)) * HH + kel;
  }

  for (int m0 = mb * 128; m0 < ne; m0 += G2_MY * 128) {
    const __hip_bfloat16* asrc[4];
#pragma unroll
    for (int i = 0; i < 4; ++i) {
      int r = ((w * 4 + i) << 3) + (lane >> 3);
      int rr = m0 + r; rr = rr < ne ? rr : ne - 1;
      asrc[i] = hbuf + (size_t)(oe + rr) * HH + kel;
    }

    f4 acc[2][8];
#pragma unroll
    for (int mf = 0; mf < 2; ++mf)
#pragma unroll
      for (int nf = 0; nf < 8; ++nf)
        acc[mf][nf] = (f4){0.f, 0.f, 0.f, 0.f};

    for (int k0 = 0; k0 < HH; k0 += 64) {
#pragma unroll
      for (int i = 0; i < 4; ++i) {
        glds16(asrc[i] + k0, As + ((w * 4 + i) << 9));
        glds16(bsrc[i] + k0, Bs + ((w * 4 + i) << 9));
      }
      __syncthreads();
#pragma unroll
      for (int kk = 0; kk < 2; ++kk) {
        const int kByte = (kk * 32 + ((lane >> 4) << 3)) * 2;
        bh8 a[2], b[8];
#pragma unroll
        for (int mf = 0; mf < 2; ++mf) {
          int row = (w << 5) + mf * 16 + (lane & 15);
          int ad = row * 128 + (kByte ^ ((row & 7) << 4));
          a[mf] = *reinterpret_cast<const bh8*>(reinterpret_cast<const char*>(As) + ad);
        }
#pragma unroll
        for (int nf = 0; nf < 8; ++nf) {
          int bn = nf * 16 + (lane & 15);
          int ad = bn * 128 + (kByte ^ ((bn & 7) << 4));
          b[nf] = *reinterpret_cast<const bh8*>(reinterpret_cast<const char*>(Bs) + ad);
        }
#pragma unroll
        for (int mf = 0; mf < 2; ++mf)
#pragma unroll
          for (int nf = 0; nf < 8; ++nf)
            acc[mf][nf] = __builtin_amdgcn_mfma_f32_16x16x32_bf16(a[mf], b[nf], acc[mf][nf], 0, 0, 0);
      }
      __syncthreads();
    }

    // epilogue: scale by gate score, write bf16 row (combined later)
#pragma unroll
    for (int mf = 0; mf < 2; ++mf) {
#pragma unroll
      for (int reg = 0; reg < 4; ++reg) {
        int grow = m0 + (w << 5) + mf * 16 + ((lane >> 4) << 2) + reg;
        if (grow < ne) {
          float sc = rows_score[oe + grow];
          __hip_bfloat16* yr = ybuf + (size_t)(oe + grow) * DD + n0 + (lane & 15);
#pragma unroll
          for (int nf = 0; nf < 8; ++nf)
            yr[nf * 16] = __float2bfloat16(sc * acc[mf][nf][reg]);
        }
      }
    }
  }
}

// ---------------- launch ----------------
extern "C" void kernel_launch(void* const* d_in, const int* in_sizes, int n_in,
                              void* d_out, int out_size, void* d_ws, size_t ws_size,
                              hipStream_t stream) {
  const float* x = (const float*)d_in[0];
  const int* topk_idx = (const int*)d_in[1];
  const float* topk_sc = (const float*)d_in[2];
  const float* Wg = (const float*)d_in[3];
  const float* Wu = (const float*)d_in[4];
  const float* Wd = (const float*)d_in[5];
  float* y = (float*)d_out;

  char* p = (char*)d_ws;
  auto take = [&](size_t b) { char* r = p; p += (b + 255) & ~(size_t)255; return r; };
  int* counts = (int*)take(EE * 4);
  int* cursor = (int*)take(EE * 4);
  int* off = (int*)take((EE + 1) * 4);
  int* rows_token = (int*)take((size_t)NA * 4);
  float* rows_score = (float*)take((size_t)NA * 4);
  int* pos = (int*)take((size_t)NA * 4);
  __hip_bfloat16* xb = (__hip_bfloat16*)take((size_t)TT * DD * 2);
  __hip_bfloat16* Wgb = (__hip_bfloat16*)take((size_t)EE * DD * HH * 2);
  __hip_bfloat16* Wub = (__hip_bfloat16*)take((size_t)EE * DD * HH * 2);
  __hip_bfloat16* Wdb = (__hip_bfloat16*)take((size_t)EE * DD * HH * 2);
  __hip_bfloat16* hbuf = (__hip_bfloat16*)take((size_t)NA * HH * 2);
  __hip_bfloat16* ybuf = (__hip_bfloat16*)take((size_t)NA * DD * 2);

  k_init<<<1, 64, 0, stream>>>(counts);
  k_count<<<NA / 256, 256, 0, stream>>>(topk_idx, counts);
  k_scan<<<1, 1, 0, stream>>>(counts, off, cursor);
  k_scatter<<<NA / 256, 256, 0, stream>>>(topk_idx, topk_sc, cursor, rows_token,
                                          rows_score, pos);
  k_cvtx<<<TT * DD / 4 / 256, 256, 0, stream>>>(x, xb);
  dim3 tg(HH / 32, DD / 32, EE);
  k_tc<<<tg, dim3(32, 8), 0, stream>>>(Wg, Wgb, DD, HH);
  k_tc<<<tg, dim3(32, 8), 0, stream>>>(Wu, Wub, DD, HH);
  dim3 td(DD / 32, HH / 32, EE);
  k_tc<<<td, dim3(32, 8), 0, stream>>>(Wd, Wdb, HH, DD);
  k_gemm1<<<G1_NX * G1_MY * EE, 256, 0, stream>>>(xb, Wgb, Wub, rows_token, off, hbuf);
  k_gemm2<<<G2_NX * G2_MY * EE, 256, 0, stream>>>(hbuf, Wdb, rows_score, off, ybuf);
  k_combine<<<TT * (DD / 8) / 256, 256, 0, stream>>>(ybuf, pos, y);
}

// Round 5
// 583.994 us; speedup vs baseline: 1.2061x; 1.1573x over previous
//
#include <hip/hip_runtime.h>
#include <hip/hip_bf16.h>

#define TT 8192
#define DD 2048
#define HH 1408
#define EE 8
#define KTOP 2
#define NA (TT * KTOP)  // 16384 assignments

typedef __attribute__((ext_vector_type(8))) short bh8;   // 8 bf16 = 4 VGPR
typedef __attribute__((ext_vector_type(4))) float f4;    // MFMA accumulator

typedef __attribute__((address_space(1))) const void gconst_t;
typedef __attribute__((address_space(3))) void lds_t;

__device__ __forceinline__ void glds16(const void* g, void* l) {
  __builtin_amdgcn_global_load_lds((gconst_t*)g, (lds_t*)l, 16, 0, 0);
}

__device__ __forceinline__ float silu_f(float x) { return x / (1.f + __expf(-x)); }

// ---------------- bookkeeping kernels ----------------
__global__ void k_init(int* counts) {
  int i = threadIdx.x;
  if (i < EE) counts[i] = 0;
}

__global__ void k_count(const int* __restrict__ idx, int* __restrict__ counts) {
  int i = blockIdx.x * 256 + threadIdx.x;
  if (i < NA) atomicAdd(&counts[idx[i]], 1);
}

__global__ void k_scan(const int* __restrict__ counts, int* __restrict__ off,
                       int* __restrict__ cursor) {
  if (threadIdx.x == 0) {
    int a = 0;
    for (int e = 0; e < EE; ++e) { off[e] = a; cursor[e] = a; a += counts[e]; }
    off[EE] = a;
  }
}

__global__ void k_scatter(const int* __restrict__ idx, const float* __restrict__ sc,
                          int* __restrict__ cursor, int* __restrict__ rows_token,
                          float* __restrict__ rows_score, int* __restrict__ pos) {
  int i = blockIdx.x * 256 + threadIdx.x;
  if (i < NA) {
    int e = idx[i];
    int p = atomicAdd(&cursor[e], 1);
    rows_token[p] = i / KTOP;
    rows_score[p] = sc[i];
    pos[i] = p;
  }
}

// ---------------- conversion kernels ----------------
__global__ void k_cvtx(const float* __restrict__ src, __hip_bfloat16* __restrict__ dst) {
  int i = blockIdx.x * 256 + threadIdx.x;  // indexes float4
  const int n4 = TT * DD / 4;
  if (i < n4) {
    float4 v = reinterpret_cast<const float4*>(src)[i];
    union { ushort4 u; __hip_bfloat16 h[4]; } o;
    o.h[0] = __float2bfloat16(v.x); o.h[1] = __float2bfloat16(v.y);
    o.h[2] = __float2bfloat16(v.z); o.h[3] = __float2bfloat16(v.w);
    reinterpret_cast<ushort4*>(dst)[i] = o.u;
  }
}

// transpose+convert: src fp32 [B][R][C] -> dst bf16 [B][C][R], 64x64 tiles.
// Loads: 16 lanes x float4 = 256 B rows. Stores: 32 B contiguous per thread,
// 128 B per output row. LDS [64][65]: 2-way bank conflicts only (free).
__global__ void k_tc(const float* __restrict__ src, __hip_bfloat16* __restrict__ dst,
                     int R, int C) {
  __shared__ float t[64][65];
  const float* s = src + (size_t)blockIdx.z * R * C;
  __hip_bfloat16* d = dst + (size_t)blockIdx.z * R * C;
  const int c0 = blockIdx.x * 64, r0 = blockIdx.y * 64;
  const int tid = threadIdx.x;
  const int lr = tid >> 4;          // 0..15
  const int lc = (tid & 15) << 2;   // float4 col
#pragma unroll
  for (int rr = 0; rr < 4; ++rr) {
    int r = lr + rr * 16;
    float4 v = *reinterpret_cast<const float4*>(&s[(size_t)(r0 + r) * C + c0 + lc]);
    t[r][lc] = v.x; t[r][lc + 1] = v.y; t[r][lc + 2] = v.z; t[r][lc + 3] = v.w;
  }
  __syncthreads();
  const int oc = tid >> 2;          // 0..63 output row (source col)
  const int ob = (tid & 3) << 4;    // 0/16/32/48 element offset within row
  __hip_bfloat16 o16[16];
#pragma unroll
  for (int k = 0; k < 16; ++k)
    o16[k] = __float2bfloat16(t[ob + k][oc]);
  __hip_bfloat16* dp = &d[(size_t)(c0 + oc) * R + r0 + ob];
  *reinterpret_cast<uint4*>(dp) = *reinterpret_cast<const uint4*>(o16);
  *reinterpret_cast<uint4*>(dp + 8) = *reinterpret_cast<const uint4*>(o16 + 8);
}

// combine: y[t] = fp32(ybuf[pos[2t]]) + fp32(ybuf[pos[2t+1]])  (scores pre-folded)
__global__ void k_combine(const __hip_bfloat16* __restrict__ ybuf,
                          const int* __restrict__ pos, float* __restrict__ y) {
  int i = blockIdx.x * 256 + threadIdx.x;  // over TT * DD/8
  int t = i >> 8;                          // DD/8 == 256
  int d0 = (i & 255) << 3;
  const uint4 a = *reinterpret_cast<const uint4*>(ybuf + (size_t)pos[2 * t] * DD + d0);
  const uint4 b = *reinterpret_cast<const uint4*>(ybuf + (size_t)pos[2 * t + 1] * DD + d0);
  float* o = y + (size_t)t * DD + d0;
  unsigned au[4] = {a.x, a.y, a.z, a.w}, bu[4] = {b.x, b.y, b.z, b.w};
  float r[8];
#pragma unroll
  for (int j = 0; j < 4; ++j) {
    r[2 * j] = __uint_as_float(au[j] << 16) + __uint_as_float(bu[j] << 16);
    r[2 * j + 1] = __uint_as_float(au[j] & 0xffff0000u) + __uint_as_float(bu[j] & 0xffff0000u);
  }
  reinterpret_cast<float4*>(o)[0] = (float4){r[0], r[1], r[2], r[3]};
  reinterpret_cast<float4*>(o)[1] = (float4){r[4], r[5], r[6], r[7]};
}

// ---------------- GEMM1: h = silu(Xe*Wg) * (Xe*Wu) ----------------
// Round-1 proven config: 128 rows x (64 gate + 64 up cols), BK=64, 4 waves,
// 3D grid (HH/64, 20, EE), n-fastest dispatch.
__global__ __launch_bounds__(256, 2) void k_gemm1(
    const __hip_bfloat16* __restrict__ xb,
    const __hip_bfloat16* __restrict__ Wgb,
    const __hip_bfloat16* __restrict__ Wub,
    const int* __restrict__ rows_token,
    const int* __restrict__ off,
    __hip_bfloat16* __restrict__ hbuf) {
  const int e = blockIdx.z;
  const int oe = off[e];
  const int ne = off[e + 1] - oe;
  if (ne <= 0) return;
  const int n0 = blockIdx.x * 64;
  const int tid = threadIdx.x;
  const int lane = tid & 63;
  const int w = tid >> 6;

  __shared__ __hip_bfloat16 As[128 * 64];
  __shared__ __hip_bfloat16 Bs[128 * 64];

  const int kel = (((lane & 7) ^ (lane >> 3)) << 3);

  const __hip_bfloat16* bsrc[4];
#pragma unroll
  for (int i = 0; i < 4; ++i) {
    int bn = ((w * 4 + i) << 3) + (lane >> 3);
    const __hip_bfloat16* base =
        (bn < 64) ? (Wgb + ((size_t)e * HH + (n0 + bn)) * DD)
                  : (Wub + ((size_t)e * HH + (n0 + bn - 64)) * DD);
    bsrc[i] = base + kel;
  }

  for (int m0 = blockIdx.y * 128; m0 < ne; m0 += gridDim.y * 128) {
    const __hip_bfloat16* asrc[4];
#pragma unroll
    for (int i = 0; i < 4; ++i) {
      int r = ((w * 4 + i) << 3) + (lane >> 3);
      int rr = m0 + r; rr = rr < ne ? rr : ne - 1;
      asrc[i] = xb + (size_t)rows_token[oe + rr] * DD + kel;
    }

    f4 acc[2][8];
#pragma unroll
    for (int mf = 0; mf < 2; ++mf)
#pragma unroll
      for (int nf = 0; nf < 8; ++nf)
        acc[mf][nf] = (f4){0.f, 0.f, 0.f, 0.f};

    for (int k0 = 0; k0 < DD; k0 += 64) {
#pragma unroll
      for (int i = 0; i < 4; ++i) {
        glds16(asrc[i] + k0, As + ((w * 4 + i) << 9));
        glds16(bsrc[i] + k0, Bs + ((w * 4 + i) << 9));
      }
      __syncthreads();
#pragma unroll
      for (int kk = 0; kk < 2; ++kk) {
        const int kByte = (kk * 32 + ((lane >> 4) << 3)) * 2;
        bh8 a[2], b[8];
#pragma unroll
        for (int mf = 0; mf < 2; ++mf) {
          int row = (w << 5) + mf * 16 + (lane & 15);
          int ad = row * 128 + (kByte ^ ((row & 7) << 4));
          a[mf] = *reinterpret_cast<const bh8*>(reinterpret_cast<const char*>(As) + ad);
        }
#pragma unroll
        for (int nf = 0; nf < 8; ++nf) {
          int bn = nf * 16 + (lane & 15);
          int ad = bn * 128 + (kByte ^ ((bn & 7) << 4));
          b[nf] = *reinterpret_cast<const bh8*>(reinterpret_cast<const char*>(Bs) + ad);
        }
#pragma unroll
        for (int mf = 0; mf < 2; ++mf)
#pragma unroll
          for (int nf = 0; nf < 8; ++nf)
            acc[mf][nf] = __builtin_amdgcn_mfma_f32_16x16x32_bf16(a[mf], b[nf], acc[mf][nf], 0, 0, 0);
      }
      __syncthreads();
    }

    const int cb = n0 + (lane & 15);
#pragma unroll
    for (int mf = 0; mf < 2; ++mf) {
#pragma unroll
      for (int reg = 0; reg < 4; ++reg) {
        int grow = m0 + (w << 5) + mf * 16 + ((lane >> 4) << 2) + reg;
        if (grow < ne) {
          size_t hb = (size_t)(oe + grow) * HH;
#pragma unroll
          for (int nf = 0; nf < 4; ++nf) {
            float g = acc[mf][nf][reg];
            float u = acc[mf][nf + 4][reg];
            hbuf[hb + cb + nf * 16] = __float2bfloat16(silu_f(g) * u);
          }
        }
      }
    }
  }
}

// ---------------- GEMM2: ybuf[row] = score * (h_e * Wd_e) in bf16 ----------------
// Round-1 structure, 3D grid (DD/128, 20, EE), atomic-free bf16 epilogue.
__global__ __launch_bounds__(256, 2) void k_gemm2(
    const __hip_bfloat16* __restrict__ hbuf,
    const __hip_bfloat16* __restrict__ Wdb,
    const float* __restrict__ rows_score,
    const int* __restrict__ off,
    __hip_bfloat16* __restrict__ ybuf) {
  const int e = blockIdx.z;
  const int oe = off[e];
  const int ne = off[e + 1] - oe;
  if (ne <= 0) return;
  const int n0 = blockIdx.x * 128;
  const int tid = threadIdx.x;
  const int lane = tid & 63;
  const int w = tid >> 6;

  __shared__ __hip_bfloat16 As[128 * 64];
  __shared__ __hip_bfloat16 Bs[128 * 64];
  const int kel = (((lane & 7) ^ (lane >> 3)) << 3);

  const __hip_bfloat16* bsrc[4];
#pragma unroll
  for (int i = 0; i < 4; ++i) {
    int bn = ((w * 4 + i) << 3) + (lane >> 3);
    bsrc[i] = Wdb + ((size_t)e * DD + (n0 + bn)) * HH + kel;
  }

  for (int m0 = blockIdx.y * 128; m0 < ne; m0 += gridDim.y * 128) {
    const __hip_bfloat16* asrc[4];
#pragma unroll
    for (int i = 0; i < 4; ++i) {
      int r = ((w * 4 + i) << 3) + (lane >> 3);
      int rr = m0 + r; rr = rr < ne ? rr : ne - 1;
      asrc[i] = hbuf + (size_t)(oe + rr) * HH + kel;
    }

    f4 acc[2][8];
#pragma unroll
    for (int mf = 0; mf < 2; ++mf)
#pragma unroll
      for (int nf = 0; nf < 8; ++nf)
        acc[mf][nf] = (f4){0.f, 0.f, 0.f, 0.f};

    for (int k0 = 0; k0 < HH; k0 += 64) {
#pragma unroll
      for (int i = 0; i < 4; ++i) {
        glds16(asrc[i] + k0, As + ((w * 4 + i) << 9));
        glds16(bsrc[i] + k0, Bs + ((w * 4 + i) << 9));
      }
      __syncthreads();
#pragma unroll
      for (int kk = 0; kk < 2; ++kk) {
        const int kByte = (kk * 32 + ((lane >> 4) << 3)) * 2;
        bh8 a[2], b[8];
#pragma unroll
        for (int mf = 0; mf < 2; ++mf) {
          int row = (w << 5) + mf * 16 + (lane & 15);
          int ad = row * 128 + (kByte ^ ((row & 7) << 4));
          a[mf] = *reinterpret_cast<const bh8*>(reinterpret_cast<const char*>(As) + ad);
        }
#pragma unroll
        for (int nf = 0; nf < 8; ++nf) {
          int bn = nf * 16 + (lane & 15);
          int ad = bn * 128 + (kByte ^ ((bn & 7) << 4));
          b[nf] = *reinterpret_cast<const bh8*>(reinterpret_cast<const char*>(Bs) + ad);
        }
#pragma unroll
        for (int mf = 0; mf < 2; ++mf)
#pragma unroll
          for (int nf = 0; nf < 8; ++nf)
            acc[mf][nf] = __builtin_amdgcn_mfma_f32_16x16x32_bf16(a[mf], b[nf], acc[mf][nf], 0, 0, 0);
      }
      __syncthreads();
    }

    // epilogue: scale by gate score, write bf16 row (combined later)
#pragma unroll
    for (int mf = 0; mf < 2; ++mf) {
#pragma unroll
      for (int reg = 0; reg < 4; ++reg) {
        int grow = m0 + (w << 5) + mf * 16 + ((lane >> 4) << 2) + reg;
        if (grow < ne) {
          float sc = rows_score[oe + grow];
          __hip_bfloat16* yr = ybuf + (size_t)(oe + grow) * DD + n0 + (lane & 15);
#pragma unroll
          for (int nf = 0; nf < 8; ++nf)
            yr[nf * 16] = __float2bfloat16(sc * acc[mf][nf][reg]);
        }
      }
    }
  }
}

// ---------------- launch ----------------
extern "C" void kernel_launch(void* const* d_in, const int* in_sizes, int n_in,
                              void* d_out, int out_size, void* d_ws, size_t ws_size,
                              hipStream_t stream) {
  const float* x = (const float*)d_in[0];
  const int* topk_idx = (const int*)d_in[1];
  const float* topk_sc = (const float*)d_in[2];
  const float* Wg = (const float*)d_in[3];
  const float* Wu = (const float*)d_in[4];
  const float* Wd = (const float*)d_in[5];
  float* y = (float*)d_out;

  char* p = (char*)d_ws;
  auto take = [&](size_t b) { char* r = p; p += (b + 255) & ~(size_t)255; return r; };
  int* counts = (int*)take(EE * 4);
  int* cursor = (int*)take(EE * 4);
  int* off = (int*)take((EE + 1) * 4);
  int* rows_token = (int*)take((size_t)NA * 4);
  float* rows_score = (float*)take((size_t)NA * 4);
  int* pos = (int*)take((size_t)NA * 4);
  __hip_bfloat16* xb = (__hip_bfloat16*)take((size_t)TT * DD * 2);
  __hip_bfloat16* Wgb = (__hip_bfloat16*)take((size_t)EE * DD * HH * 2);
  __hip_bfloat16* Wub = (__hip_bfloat16*)take((size_t)EE * DD * HH * 2);
  __hip_bfloat16* Wdb = (__hip_bfloat16*)take((size_t)EE * DD * HH * 2);
  __hip_bfloat16* hbuf = (__hip_bfloat16*)take((size_t)NA * HH * 2);
  __hip_bfloat16* ybuf = (__hip_bfloat16*)take((size_t)NA * DD * 2);

  k_init<<<1, 64, 0, stream>>>(counts);
  k_count<<<NA / 256, 256, 0, stream>>>(topk_idx, counts);
  k_scan<<<1, 1, 0, stream>>>(counts, off, cursor);
  k_scatter<<<NA / 256, 256, 0, stream>>>(topk_idx, topk_sc, cursor, rows_token,
                                          rows_score, pos);
  k_cvtx<<<TT * DD / 4 / 256, 256, 0, stream>>>(x, xb);
  dim3 tg(HH / 64, DD / 64, EE);
  k_tc<<<tg, 256, 0, stream>>>(Wg, Wgb, DD, HH);
  k_tc<<<tg, 256, 0, stream>>>(Wu, Wub, DD, HH);
  dim3 td(DD / 64, HH / 64, EE);
  k_tc<<<td, 256, 0, stream>>>(Wd, Wdb, HH, DD);
  k_gemm1<<<dim3(HH / 64, 20, EE), 256, 0, stream>>>(xb, Wgb, Wub, rows_token, off, hbuf);
  k_gemm2<<<dim3(DD / 128, 20, EE), 256, 0, stream>>>(hbuf, Wdb, rows_score, off, ybuf);
  k_combine<<<TT * (DD / 8) / 256, 256, 0, stream>>>(ybuf, pos, y);
}